// Round 8
// baseline (368.622 us; speedup 1.0000x reference)
//
#include <hip/hip_runtime.h>
#include <stdint.h>
#include <math.h>

// Problem geometry (fixed by reference)
#define HWPIX 65536         // 256*256
#define NCH   18
#define NHYP  1024
#define NK    9
#define NBK   72            // B*K = 8*9
#define INV_LOG2 1.4426950408889634f
#define TINYF 1.1754943508222875e-38f

// pixel part: 2048 blocks = [side(2)][b(8)][half(2)][blk64(64)], 256 thr
// hyp part:   144 blocks appended (bid 2048..2191)
#define NPIXB 2048
#define NTOTB (NPIXB + 2 * NBK)
#define NVB_SIDE 1024       // vote partials per side
#define NSB_SIDE 512        // seg/cnt partials per side (half==0 blocks)

// ws layout (floats); ws[0] = completion counter (int), zeroed by memset node
#define OFS_VOTE 64                          // [2][NVB_SIDE]
#define OFS_CNT  (OFS_VOTE + 2 * NVB_SIDE)   // [2][NSB_SIDE]
#define OFS_SEG  (OFS_CNT  + 2 * NSB_SIDE)   // [2][NSB_SIDE]
#define OFS_KP   (OFS_SEG  + 2 * NSB_SIDE)   // [2][NBK]
#define OFS_ENT  (OFS_KP   + 2 * NBK)        // [2][NBK]
#define OFS_Y    (OFS_ENT  + 2 * NBK)        // [2][NBK]

// native clang vector types (accepted by __builtin_nontemporal_load)
typedef float fx4 __attribute__((ext_vector_type(4)));
typedef int   ix4 __attribute__((ext_vector_type(4)));

// ---- Threefry-2x32, 20 rounds (JAX-compatible) ----
__host__ __device__ inline void tf2x32(uint32_t k0, uint32_t k1,
                                       uint32_t x0, uint32_t x1,
                                       uint32_t& o0, uint32_t& o1) {
  uint32_t ks2 = k0 ^ k1 ^ 0x1BD11BDAu;
  x0 += k0; x1 += k1;
#define TFR(r) { x0 += x1; x1 = (x1 << (r)) | (x1 >> (32 - (r))); x1 ^= x0; }
  TFR(13) TFR(15) TFR(26) TFR(6)   x0 += k1;  x1 += ks2 + 1u;
  TFR(17) TFR(29) TFR(16) TFR(24)  x0 += ks2; x1 += k0 + 2u;
  TFR(13) TFR(15) TFR(26) TFR(6)   x0 += k0;  x1 += k1 + 3u;
  TFR(17) TFR(29) TFR(16) TFR(24)  x0 += k1;  x1 += ks2 + 4u;
  TFR(13) TFR(15) TFR(26) TFR(6)   x0 += ks2; x1 += k0 + 5u;
#undef TFR
  o0 = x0; o1 = x1;
}

__device__ inline float blk_sum(float v, float* sm) {
  int t = threadIdx.x;
  sm[t] = v; __syncthreads();
  for (int off = 128; off > 0; off >>= 1) {
    if (t < off) sm[t] += sm[t + off];
    __syncthreads();
  }
  float r = sm[0]; __syncthreads();
  return r;
}

__device__ inline float sl1(float x, float y, float w) {
  const float dd = fabsf(x - y) * w;
  return (dd < 1.f) ? 0.5f * dd * dd : dd - 0.5f;
}

__device__ inline float nll2(float s0, float s1, int lbl) {
  const float mx = fmaxf(s0, s1);
  const float mn = fminf(s0, s1);
  const float l = mx + logf(1.0f + expf(mn - mx));
  return l - (lbl ? s1 : s0);
}

// non-temporal (L2-bypass) vector loads for streamed data
__device__ inline fx4 ldnt4(const float* p) {
  return __builtin_nontemporal_load((const fx4*)p);
}
__device__ inline ix4 ldnt4i(const int* p) {
  return __builtin_nontemporal_load((const ix4*)p);
}

// ---- Fused kernel: pixel blocks + hyp blocks + elected final reduce ----
__global__ __launch_bounds__(256, 8) void fused_kernel(
    const float* __restrict__ vpL, const float* __restrict__ vgL,
    const int*   __restrict__ mkL, const float* __restrict__ sgL,
    const float* __restrict__ vpR, const float* __restrict__ vgR,
    const int*   __restrict__ mkR, const float* __restrict__ sgR,
    const float* __restrict__ scL, const float* __restrict__ kpL,
    const float* __restrict__ k2L, const float* __restrict__ ofL,
    const float* __restrict__ scR, const float* __restrict__ kpR,
    const float* __restrict__ k2R, const float* __restrict__ ofR,
    const float* __restrict__ aPtr, const int* __restrict__ epochPtr,
    uint32_t kLa, uint32_t kLb, uint32_t kRa, uint32_t kRb,
    float* __restrict__ ws, float* __restrict__ out) {
  const int t   = threadIdx.x;
  const int bid = blockIdx.x;
  __shared__ float sm[256];
  __shared__ int   si[256];

  if (bid < NPIXB) {
    // ================= pixel path (identical to R6's 47.4µs config) ========
    const int side  = bid >> 10;
    const int v     = bid & 1023;
    const int b     = v >> 7;
    const int half  = (v >> 6) & 1;
    const int blk64 = v & 63;
    const int hwq   = blk64 * 256 + t;     // quad index 0..16383

    const float* vp = side ? vpR : vpL;
    const float* vg = side ? vgR : vgL;
    const int*   mk = side ? mkR : mkL;
    const float* sg = side ? sgR : sgL;

    // mask once
    const ix4 m4 = ldnt4i(mk + ((size_t)b << 16) + ((size_t)hwq << 2));
    const float w0 = (float)m4.x, w1 = (float)m4.y, w2 = (float)m4.z, w3 = (float)m4.w;

    // seg loads issued early (half==0 blocks only)
    fx4 s0 = (fx4)0.f, s1 = (fx4)0.f;
    if (half == 0) {
      const size_t soff = ((size_t)b << 17) + ((size_t)hwq << 2);
      s0 = ldnt4(sg + soff);
      s1 = ldnt4(sg + soff + HWPIX);
    }

    // channel walk: c = half*9 + j, j = 0..8
    const size_t pbase = ((size_t)(b * NCH + half * 9) << 16) + ((size_t)hwq << 2);
    const float* pp = vp + pbase;
    const float* qq = vg + pbase;

    fx4 Pa = ldnt4(pp);              fx4 Qa = ldnt4(qq);
    fx4 Pb = ldnt4(pp + HWPIX);      fx4 Qb = ldnt4(qq + HWPIX);

    float acc = 0.f;
#pragma unroll
    for (int j = 0; j < 9; ++j) {
      fx4 pc, qc;
      if ((j & 1) == 0) {
        pc = Pa; qc = Qa;
        if (j + 2 < 9) { Pa = ldnt4(pp + (size_t)(j + 2) * HWPIX); Qa = ldnt4(qq + (size_t)(j + 2) * HWPIX); }
      } else {
        pc = Pb; qc = Qb;
        if (j + 2 < 9) { Pb = ldnt4(pp + (size_t)(j + 2) * HWPIX); Qb = ldnt4(qq + (size_t)(j + 2) * HWPIX); }
      }
      acc += sl1(pc.x, qc.x, w0);
      acc += sl1(pc.y, qc.y, w1);
      acc += sl1(pc.z, qc.z, w2);
      acc += sl1(pc.w, qc.w, w3);
    }

    const float rvote = blk_sum(acc, sm);
    if (t == 0) ws[OFS_VOTE + side * NVB_SIDE + v] = rvote;

    if (half == 0) {
      float seg = 0.f;
      seg += nll2(s0.x, s1.x, m4.x);
      seg += nll2(s0.y, s1.y, m4.y);
      seg += nll2(s0.z, s1.z, m4.z);
      seg += nll2(s0.w, s1.w, m4.w);
      const float cnt = w0 + w1 + w2 + w3;
      const float rcnt = blk_sum(cnt, sm);
      const float rseg = blk_sum(seg, sm);
      if (t == 0) {
        const int s = b * 64 + blk64;
        ws[OFS_CNT + side * NSB_SIDE + s] = rcnt;
        ws[OFS_SEG + side * NSB_SIDE + s] = rseg;
      }
    }
  } else {
    // ================= hyp path =================
    const int hid  = bid - NPIXB;       // 0..143
    const int side = hid / NBK;
    const int bk   = hid % NBK;         // 0..71
    const float* sc = side ? scR : scL;
    const float* kp = side ? kpR : kpL;
    const float* k2 = side ? k2R : k2L;
    const float* of = side ? ofR : ofL;
    const uint32_t K0 = side ? kRa : kLa;
    const uint32_t K1 = side ? kRb : kLb;
    const int b = bk / NK, k = bk % NK;
    const float a = aPtr[0];
    const float kx = k2[(b * NK + k) * 2 + 0];
    const float ky = k2[(b * NK + k) * 2 + 1];
    const float2* kp2 = (const float2*)kp;

    float s[4], d[4], gv[4];
#pragma unroll
    for (int j = 0; j < 4; ++j) {
      const int n = t + j * 256;
      const size_t idx = ((size_t)b * NHYP + n) * NK + k;   // flat index of (b,n,k)
      s[j] = a * sc[idx];
      const float2 xy = kp2[idx];
      const float dx = xy.x - kx, dy = xy.y - ky;
      d[j] = sqrtf(dx * dx + dy * dy);
      // JAX partitionable random bits: bits = out0 ^ out1 of threefry(key, (0, flat_idx))
      uint32_t o0, o1;
      tf2x32(K0, K1, 0u, (uint32_t)idx, o0, o1);
      const uint32_t bits = o0 ^ o1;
      float u = __uint_as_float((bits >> 9) | 0x3F800000u) - 1.0f;   // [0,1)
      u = fmaxf(TINYF, u * (1.0f - TINYF) + TINYF);                  // uniform(tiny, 1)
      gv[j] = -logf(-logf(u)) + s[j];                                // gumbel + logits
    }

    // block max of logits
    float mx = fmaxf(fmaxf(s[0], s[1]), fmaxf(s[2], s[3]));
    sm[t] = mx; __syncthreads();
    for (int off = 128; off > 0; off >>= 1) {
      if (t < off) sm[t] = fmaxf(sm[t], sm[t + off]);
      __syncthreads();
    }
    mx = sm[0]; __syncthreads();

    float Z = 0.f, Sd = 0.f, Ss = 0.f;
#pragma unroll
    for (int j = 0; j < 4; ++j) {
      const float e = expf(s[j] - mx);
      Z  += e;
      Sd += e * d[j];
      Ss += e * (s[j] - mx);
    }
    Z  = blk_sum(Z, sm);
    Sd = blk_sum(Sd, sm);
    Ss = blk_sum(Ss, sm);

    // argmax of gumbel+logits, first-index tie-break (matches jnp.argmax)
    float bv = gv[0]; int bi = t;
#pragma unroll
    for (int j = 1; j < 4; ++j) {
      const int n = t + j * 256;
      if (gv[j] > bv) { bv = gv[j]; bi = n; }
    }
    sm[t] = bv; si[t] = bi; __syncthreads();
    for (int off = 128; off > 0; off >>= 1) {
      if (t < off) {
        const float v2 = sm[t + off]; const int i2 = si[t + off];
        if (v2 > sm[t] || (v2 == sm[t] && i2 < si[t])) { sm[t] = v2; si[t] = i2; }
      }
      __syncthreads();
    }

    if (t == 0) {
      ws[OFS_KP  + side * NBK + bk] = Sd / Z;
      ws[OFS_ENT + side * NBK + bk] = (logf(Z) - Ss / Z) * INV_LOG2;  // entropy bits
      const int n = si[0];
      ws[OFS_Y + side * NBK + bk] =
          kp2[((size_t)b * NHYP + n) * NK + k].y + of[b * 2 + 1];
    }
  }

  // ============ completion count; elected (last) block runs final reduce ====
  __shared__ int isLast;
  __threadfence();                        // release partials device-wide
  if (t == 0) {
    const int c = atomicAdd((int*)ws, 1); // ws[0] zeroed by memset node
    isLast = (c == NTOTB - 1);
  }
  __syncthreads();
  if (!isLast) return;
  __threadfence();                        // acquire all partials

  float voteS[2], cntS[2], segS[2], kpS[2], entS[2];
  for (int side = 0; side < 2; ++side) {
    float a;
    a = 0.f; for (int j = t; j < NVB_SIDE; j += 256) a += ws[OFS_VOTE + side * NVB_SIDE + j];
    voteS[side] = blk_sum(a, sm);
    a = 0.f; for (int j = t; j < NSB_SIDE; j += 256) a += ws[OFS_CNT + side * NSB_SIDE + j];
    cntS[side] = blk_sum(a, sm);
    a = 0.f; for (int j = t; j < NSB_SIDE; j += 256) a += ws[OFS_SEG + side * NSB_SIDE + j];
    segS[side] = blk_sum(a, sm);
    a = (t < NBK) ? ws[OFS_KP + side * NBK + t] : 0.f;
    kpS[side] = blk_sum(a, sm);
    a = 0.f;
    if (t < 8) {
      float es = 0.f;
      for (int k = 0; k < NK; ++k) es += ws[OFS_ENT + side * NBK + t * NK + k];
      a = fabsf(es / (float)NK - 6.0f);
    }
    entS[side] = blk_sum(a, sm);
  }
  float e = 0.f;
  if (t < NBK) {
    const float dy = fabsf(ws[OFS_Y + t] - ws[OFS_Y + NBK + t]);
    e = isfinite(dy) ? dy : 0.f;
  }
  const float epiSum = blk_sum(e, sm);

  if (t == 0) {
    const float voteL = (cntS[0] > 0.f) ? voteS[0] / fmaxf(cntS[0], 1.f) / (float)NCH : voteS[0];
    const float voteR = (cntS[1] > 0.f) ? voteS[1] / fmaxf(cntS[1], 1.f) / (float)NCH : voteS[1];
    const float segL = segS[0] / 524288.f;
    const float segR = segS[1] / 524288.f;
    const float kpLm = kpS[0] / (float)NBK, kpRm = kpS[1] / (float)NBK;
    const float entL = entS[0] / 8.f, entR = entS[1] / 8.f;

    const float vote_loss = 0.5f * (voteL + voteR);
    const float seg_loss  = 0.5f * (segL + segR);
    const float kp_loss   = 0.5f * (kpLm + kpRm);
    const float ent_loss  = 0.5f * (entL + entR);
    const float kp_w  = 1.f / (1.f + expf(-0.5f * (20.f - kp_loss)));
    const float vote_w = 1.f - kp_w;
    float vertex;
    if (epochPtr[0] > 49) {
      const float epi = epiSum / (float)NBK;
      vertex = kp_w * (kp_loss + epi) + vote_w * vote_loss;
    } else {
      vertex = kp_w * kp_loss + vote_w * vote_loss;
    }
    out[0] = vertex + ent_loss + seg_loss;
  }
}

extern "C" void kernel_launch(void* const* d_in, const int* in_sizes, int n_in,
                              void* d_out, int out_size, void* d_ws, size_t ws_size,
                              hipStream_t stream) {
  (void)in_sizes; (void)n_in; (void)out_size; (void)ws_size;
  const float* vpL = (const float*)d_in[0];
  const float* vgL = (const float*)d_in[1];
  const int*   mkL = (const int*)  d_in[2];
  const float* sgL = (const float*)d_in[3];
  const float* kpL = (const float*)d_in[4];
  const float* scL = (const float*)d_in[5];
  const float* k2L = (const float*)d_in[6];
  const float* ofL = (const float*)d_in[7];
  const float* vpR = (const float*)d_in[8];
  const float* vgR = (const float*)d_in[9];
  const int*   mkR = (const int*)  d_in[10];
  const float* sgR = (const float*)d_in[11];
  const float* kpR = (const float*)d_in[12];
  const float* scR = (const float*)d_in[13];
  const float* k2R = (const float*)d_in[14];
  const float* ofR = (const float*)d_in[15];
  const float* aP  = (const float*)d_in[16];
  const int*   epP = (const int*)  d_in[17];
  float* ws  = (float*)d_ws;
  float* out = (float*)d_out;

  // jax.random.split(jax.random.key(1234)) — partitionable ("foldlike") split:
  // kL = threefry(key, (0,0)), kR = threefry(key, (0,1)), key = [0, 1234]
  uint32_t kLa, kLb, kRa, kRb;
  tf2x32(0u, 1234u, 0u, 0u, kLa, kLb);
  tf2x32(0u, 1234u, 0u, 1u, kRa, kRb);

  // zero the completion counter (graph-capturable memset node)
  hipMemsetAsync(ws, 0, sizeof(int), stream);

  fused_kernel<<<NTOTB, 256, 0, stream>>>(
      vpL, vgL, mkL, sgL, vpR, vgR, mkR, sgR,
      scL, kpL, k2L, ofL, scR, kpR, k2R, ofR,
      aP, epP, kLa, kLb, kRa, kRb, ws, out);
}

// Round 9
// 65.640 us; speedup vs baseline: 5.6158x; 5.6158x over previous
//
#include <hip/hip_runtime.h>
#include <stdint.h>
#include <math.h>

// Problem geometry (fixed by reference)
#define HWPIX 65536         // 256*256
#define NCH   18
#define NHYP  1024
#define NK    9
#define NBK   72            // B*K = 8*9
#define INV_LOG2 1.4426950408889634f
#define TINYF 1.1754943508222875e-38f

// pixel part: 2048 blocks = [side(2)][b(8)][half(2)][blk64(64)], 256 thr
// hyp part:   144 blocks appended (bid 2048..2191)
#define NPIXB 2048
#define NTOTB (NPIXB + 2 * NBK)
#define NVB_SIDE 1024       // vote partials per side
#define NSB_SIDE 512        // seg/cnt partials per side (half==0 blocks)

// ws layout (floats); ws[0] = completion counter (int), zeroed by memset node
#define OFS_VOTE 64                          // [2][NVB_SIDE]
#define OFS_CNT  (OFS_VOTE + 2 * NVB_SIDE)   // [2][NSB_SIDE]
#define OFS_SEG  (OFS_CNT  + 2 * NSB_SIDE)   // [2][NSB_SIDE]
#define OFS_KP   (OFS_SEG  + 2 * NSB_SIDE)   // [2][NBK]
#define OFS_ENT  (OFS_KP   + 2 * NBK)        // [2][NBK]
#define OFS_Y    (OFS_ENT  + 2 * NBK)        // [2][NBK]

// native clang vector types (accepted by __builtin_nontemporal_load)
typedef float fx4 __attribute__((ext_vector_type(4)));
typedef int   ix4 __attribute__((ext_vector_type(4)));

// ---- Threefry-2x32, 20 rounds (JAX-compatible) ----
__host__ __device__ inline void tf2x32(uint32_t k0, uint32_t k1,
                                       uint32_t x0, uint32_t x1,
                                       uint32_t& o0, uint32_t& o1) {
  uint32_t ks2 = k0 ^ k1 ^ 0x1BD11BDAu;
  x0 += k0; x1 += k1;
#define TFR(r) { x0 += x1; x1 = (x1 << (r)) | (x1 >> (32 - (r))); x1 ^= x0; }
  TFR(13) TFR(15) TFR(26) TFR(6)   x0 += k1;  x1 += ks2 + 1u;
  TFR(17) TFR(29) TFR(16) TFR(24)  x0 += ks2; x1 += k0 + 2u;
  TFR(13) TFR(15) TFR(26) TFR(6)   x0 += k0;  x1 += k1 + 3u;
  TFR(17) TFR(29) TFR(16) TFR(24)  x0 += k1;  x1 += ks2 + 4u;
  TFR(13) TFR(15) TFR(26) TFR(6)   x0 += ks2; x1 += k0 + 5u;
#undef TFR
  o0 = x0; o1 = x1;
}

__device__ inline float blk_sum(float v, float* sm) {
  int t = threadIdx.x;
  sm[t] = v; __syncthreads();
  for (int off = 128; off > 0; off >>= 1) {
    if (t < off) sm[t] += sm[t + off];
    __syncthreads();
  }
  float r = sm[0]; __syncthreads();
  return r;
}

__device__ inline float sl1(float x, float y, float w) {
  const float dd = fabsf(x - y) * w;
  return (dd < 1.f) ? 0.5f * dd * dd : dd - 0.5f;
}

__device__ inline float nll2(float s0, float s1, int lbl) {
  const float mx = fmaxf(s0, s1);
  const float mn = fminf(s0, s1);
  const float l = mx + logf(1.0f + expf(mn - mx));
  return l - (lbl ? s1 : s0);
}

// non-temporal (L2-bypass) vector loads for streamed data
__device__ inline fx4 ldnt4(const float* p) {
  return __builtin_nontemporal_load((const fx4*)p);
}
__device__ inline ix4 ldnt4i(const int* p) {
  return __builtin_nontemporal_load((const ix4*)p);
}

// flush-free cross-XCD communication: system-scope relaxed atomics
// (sc0 sc1 encoded on the instruction — coherence point, NO cache flushes)
__device__ inline void st_sys(float* p, float v) {
  __hip_atomic_store(p, v, __ATOMIC_RELAXED, __HIP_MEMORY_SCOPE_SYSTEM);
}
__device__ inline float ld_sys(const float* p) {
  return __hip_atomic_load(p, __ATOMIC_RELAXED, __HIP_MEMORY_SCOPE_SYSTEM);
}

// ---- Fused kernel: pixel blocks + hyp blocks + elected final reduce ----
__global__ __launch_bounds__(256, 8) void fused_kernel(
    const float* __restrict__ vpL, const float* __restrict__ vgL,
    const int*   __restrict__ mkL, const float* __restrict__ sgL,
    const float* __restrict__ vpR, const float* __restrict__ vgR,
    const int*   __restrict__ mkR, const float* __restrict__ sgR,
    const float* __restrict__ scL, const float* __restrict__ kpL,
    const float* __restrict__ k2L, const float* __restrict__ ofL,
    const float* __restrict__ scR, const float* __restrict__ kpR,
    const float* __restrict__ k2R, const float* __restrict__ ofR,
    const float* __restrict__ aPtr, const int* __restrict__ epochPtr,
    uint32_t kLa, uint32_t kLb, uint32_t kRa, uint32_t kRb,
    float* __restrict__ ws, float* __restrict__ out) {
  const int t   = threadIdx.x;
  const int bid = blockIdx.x;
  __shared__ float sm[256];
  __shared__ int   si[256];

  if (bid < NPIXB) {
    // ================= pixel path (identical to R6's proven config) ========
    const int side  = bid >> 10;
    const int v     = bid & 1023;
    const int b     = v >> 7;
    const int half  = (v >> 6) & 1;
    const int blk64 = v & 63;
    const int hwq   = blk64 * 256 + t;     // quad index 0..16383

    const float* vp = side ? vpR : vpL;
    const float* vg = side ? vgR : vgL;
    const int*   mk = side ? mkR : mkL;
    const float* sg = side ? sgR : sgL;

    // mask once
    const ix4 m4 = ldnt4i(mk + ((size_t)b << 16) + ((size_t)hwq << 2));
    const float w0 = (float)m4.x, w1 = (float)m4.y, w2 = (float)m4.z, w3 = (float)m4.w;

    // seg loads issued early (half==0 blocks only)
    fx4 s0 = (fx4)0.f, s1 = (fx4)0.f;
    if (half == 0) {
      const size_t soff = ((size_t)b << 17) + ((size_t)hwq << 2);
      s0 = ldnt4(sg + soff);
      s1 = ldnt4(sg + soff + HWPIX);
    }

    // channel walk: c = half*9 + j, j = 0..8
    const size_t pbase = ((size_t)(b * NCH + half * 9) << 16) + ((size_t)hwq << 2);
    const float* pp = vp + pbase;
    const float* qq = vg + pbase;

    fx4 Pa = ldnt4(pp);              fx4 Qa = ldnt4(qq);
    fx4 Pb = ldnt4(pp + HWPIX);      fx4 Qb = ldnt4(qq + HWPIX);

    float acc = 0.f;
#pragma unroll
    for (int j = 0; j < 9; ++j) {
      fx4 pc, qc;
      if ((j & 1) == 0) {
        pc = Pa; qc = Qa;
        if (j + 2 < 9) { Pa = ldnt4(pp + (size_t)(j + 2) * HWPIX); Qa = ldnt4(qq + (size_t)(j + 2) * HWPIX); }
      } else {
        pc = Pb; qc = Qb;
        if (j + 2 < 9) { Pb = ldnt4(pp + (size_t)(j + 2) * HWPIX); Qb = ldnt4(qq + (size_t)(j + 2) * HWPIX); }
      }
      acc += sl1(pc.x, qc.x, w0);
      acc += sl1(pc.y, qc.y, w1);
      acc += sl1(pc.z, qc.z, w2);
      acc += sl1(pc.w, qc.w, w3);
    }

    const float rvote = blk_sum(acc, sm);
    if (t == 0) st_sys(&ws[OFS_VOTE + side * NVB_SIDE + v], rvote);

    if (half == 0) {
      float seg = 0.f;
      seg += nll2(s0.x, s1.x, m4.x);
      seg += nll2(s0.y, s1.y, m4.y);
      seg += nll2(s0.z, s1.z, m4.z);
      seg += nll2(s0.w, s1.w, m4.w);
      const float cnt = w0 + w1 + w2 + w3;
      const float rcnt = blk_sum(cnt, sm);
      const float rseg = blk_sum(seg, sm);
      if (t == 0) {
        const int s = b * 64 + blk64;
        st_sys(&ws[OFS_CNT + side * NSB_SIDE + s], rcnt);
        st_sys(&ws[OFS_SEG + side * NSB_SIDE + s], rseg);
      }
    }
  } else {
    // ================= hyp path =================
    const int hid  = bid - NPIXB;       // 0..143
    const int side = hid / NBK;
    const int bk   = hid % NBK;         // 0..71
    const float* sc = side ? scR : scL;
    const float* kp = side ? kpR : kpL;
    const float* k2 = side ? k2R : k2L;
    const float* of = side ? ofR : ofL;
    const uint32_t K0 = side ? kRa : kLa;
    const uint32_t K1 = side ? kRb : kLb;
    const int b = bk / NK, k = bk % NK;
    const float a = aPtr[0];
    const float kx = k2[(b * NK + k) * 2 + 0];
    const float ky = k2[(b * NK + k) * 2 + 1];
    const float2* kp2 = (const float2*)kp;

    float s[4], d[4], gv[4];
#pragma unroll
    for (int j = 0; j < 4; ++j) {
      const int n = t + j * 256;
      const size_t idx = ((size_t)b * NHYP + n) * NK + k;   // flat index of (b,n,k)
      s[j] = a * sc[idx];
      const float2 xy = kp2[idx];
      const float dx = xy.x - kx, dy = xy.y - ky;
      d[j] = sqrtf(dx * dx + dy * dy);
      // JAX partitionable random bits: bits = out0 ^ out1 of threefry(key, (0, flat_idx))
      uint32_t o0, o1;
      tf2x32(K0, K1, 0u, (uint32_t)idx, o0, o1);
      const uint32_t bits = o0 ^ o1;
      float u = __uint_as_float((bits >> 9) | 0x3F800000u) - 1.0f;   // [0,1)
      u = fmaxf(TINYF, u * (1.0f - TINYF) + TINYF);                  // uniform(tiny, 1)
      gv[j] = -logf(-logf(u)) + s[j];                                // gumbel + logits
    }

    // block max of logits
    float mx = fmaxf(fmaxf(s[0], s[1]), fmaxf(s[2], s[3]));
    sm[t] = mx; __syncthreads();
    for (int off = 128; off > 0; off >>= 1) {
      if (t < off) sm[t] = fmaxf(sm[t], sm[t + off]);
      __syncthreads();
    }
    mx = sm[0]; __syncthreads();

    float Z = 0.f, Sd = 0.f, Ss = 0.f;
#pragma unroll
    for (int j = 0; j < 4; ++j) {
      const float e = expf(s[j] - mx);
      Z  += e;
      Sd += e * d[j];
      Ss += e * (s[j] - mx);
    }
    Z  = blk_sum(Z, sm);
    Sd = blk_sum(Sd, sm);
    Ss = blk_sum(Ss, sm);

    // argmax of gumbel+logits, first-index tie-break (matches jnp.argmax)
    float bv = gv[0]; int bi = t;
#pragma unroll
    for (int j = 1; j < 4; ++j) {
      const int n = t + j * 256;
      if (gv[j] > bv) { bv = gv[j]; bi = n; }
    }
    sm[t] = bv; si[t] = bi; __syncthreads();
    for (int off = 128; off > 0; off >>= 1) {
      if (t < off) {
        const float v2 = sm[t + off]; const int i2 = si[t + off];
        if (v2 > sm[t] || (v2 == sm[t] && i2 < si[t])) { sm[t] = v2; si[t] = i2; }
      }
      __syncthreads();
    }

    if (t == 0) {
      st_sys(&ws[OFS_KP  + side * NBK + bk], Sd / Z);
      st_sys(&ws[OFS_ENT + side * NBK + bk], (logf(Z) - Ss / Z) * INV_LOG2);
      const int n = si[0];
      st_sys(&ws[OFS_Y + side * NBK + bk],
             kp2[((size_t)b * NHYP + n) * NK + k].y + of[b * 2 + 1]);
    }
  }

  // ==== completion count (flush-free); elected last block runs final reduce ==
  __shared__ int isLast;
  if (t == 0) {
    asm volatile("s_waitcnt vmcnt(0)" ::: "memory");  // sc1 stores committed
    const int c = __hip_atomic_fetch_add((int*)ws, 1, __ATOMIC_RELAXED,
                                         __HIP_MEMORY_SCOPE_SYSTEM);
    isLast = (c == NTOTB - 1);
  }
  __syncthreads();
  if (!isLast) return;

  float voteS[2], cntS[2], segS[2], kpS[2], entS[2];
  for (int side = 0; side < 2; ++side) {
    float a;
    a = 0.f; for (int j = t; j < NVB_SIDE; j += 256) a += ld_sys(&ws[OFS_VOTE + side * NVB_SIDE + j]);
    voteS[side] = blk_sum(a, sm);
    a = 0.f; for (int j = t; j < NSB_SIDE; j += 256) a += ld_sys(&ws[OFS_CNT + side * NSB_SIDE + j]);
    cntS[side] = blk_sum(a, sm);
    a = 0.f; for (int j = t; j < NSB_SIDE; j += 256) a += ld_sys(&ws[OFS_SEG + side * NSB_SIDE + j]);
    segS[side] = blk_sum(a, sm);
    a = (t < NBK) ? ld_sys(&ws[OFS_KP + side * NBK + t]) : 0.f;
    kpS[side] = blk_sum(a, sm);
    a = 0.f;
    if (t < 8) {
      float es = 0.f;
      for (int k = 0; k < NK; ++k) es += ld_sys(&ws[OFS_ENT + side * NBK + t * NK + k]);
      a = fabsf(es / (float)NK - 6.0f);
    }
    entS[side] = blk_sum(a, sm);
  }
  float e = 0.f;
  if (t < NBK) {
    const float dy = fabsf(ld_sys(&ws[OFS_Y + t]) - ld_sys(&ws[OFS_Y + NBK + t]));
    e = isfinite(dy) ? dy : 0.f;
  }
  const float epiSum = blk_sum(e, sm);

  if (t == 0) {
    const float voteL = (cntS[0] > 0.f) ? voteS[0] / fmaxf(cntS[0], 1.f) / (float)NCH : voteS[0];
    const float voteR = (cntS[1] > 0.f) ? voteS[1] / fmaxf(cntS[1], 1.f) / (float)NCH : voteS[1];
    const float segL = segS[0] / 524288.f;
    const float segR = segS[1] / 524288.f;
    const float kpLm = kpS[0] / (float)NBK, kpRm = kpS[1] / (float)NBK;
    const float entL = entS[0] / 8.f, entR = entS[1] / 8.f;

    const float vote_loss = 0.5f * (voteL + voteR);
    const float seg_loss  = 0.5f * (segL + segR);
    const float kp_loss   = 0.5f * (kpLm + kpRm);
    const float ent_loss  = 0.5f * (entL + entR);
    const float kp_w  = 1.f / (1.f + expf(-0.5f * (20.f - kp_loss)));
    const float vote_w = 1.f - kp_w;
    float vertex;
    if (epochPtr[0] > 49) {
      const float epi = epiSum / (float)NBK;
      vertex = kp_w * (kp_loss + epi) + vote_w * vote_loss;
    } else {
      vertex = kp_w * kp_loss + vote_w * vote_loss;
    }
    out[0] = vertex + ent_loss + seg_loss;
  }
}

extern "C" void kernel_launch(void* const* d_in, const int* in_sizes, int n_in,
                              void* d_out, int out_size, void* d_ws, size_t ws_size,
                              hipStream_t stream) {
  (void)in_sizes; (void)n_in; (void)out_size; (void)ws_size;
  const float* vpL = (const float*)d_in[0];
  const float* vgL = (const float*)d_in[1];
  const int*   mkL = (const int*)  d_in[2];
  const float* sgL = (const float*)d_in[3];
  const float* kpL = (const float*)d_in[4];
  const float* scL = (const float*)d_in[5];
  const float* k2L = (const float*)d_in[6];
  const float* ofL = (const float*)d_in[7];
  const float* vpR = (const float*)d_in[8];
  const float* vgR = (const float*)d_in[9];
  const int*   mkR = (const int*)  d_in[10];
  const float* sgR = (const float*)d_in[11];
  const float* kpR = (const float*)d_in[12];
  const float* scR = (const float*)d_in[13];
  const float* k2R = (const float*)d_in[14];
  const float* ofR = (const float*)d_in[15];
  const float* aP  = (const float*)d_in[16];
  const int*   epP = (const int*)  d_in[17];
  float* ws  = (float*)d_ws;
  float* out = (float*)d_out;

  // jax.random.split(jax.random.key(1234)) — partitionable ("foldlike") split:
  // kL = threefry(key, (0,0)), kR = threefry(key, (0,1)), key = [0, 1234]
  uint32_t kLa, kLb, kRa, kRb;
  tf2x32(0u, 1234u, 0u, 0u, kLa, kLb);
  tf2x32(0u, 1234u, 0u, 1u, kRa, kRb);

  // zero the completion counter (graph-capturable memset node)
  hipMemsetAsync(ws, 0, sizeof(int), stream);

  fused_kernel<<<NTOTB, 256, 0, stream>>>(
      vpL, vgL, mkL, sgL, vpR, vgR, mkR, sgR,
      scL, kpL, k2L, ofL, scR, kpR, k2R, ofR,
      aP, epP, kLa, kLb, kRa, kRb, ws, out);
}

// Round 10
// 63.290 us; speedup vs baseline: 5.8243x; 1.0371x over previous
//
#include <hip/hip_runtime.h>
#include <stdint.h>
#include <math.h>

// Problem geometry (fixed by reference)
#define HWPIX 65536         // 256*256
#define NCH   18
#define NHYP  1024
#define NK    9
#define NBK   72            // B*K = 8*9
#define INV_LOG2 1.4426950408889634f
#define TINYF 1.1754943508222875e-38f

// hyp part: blocks 0..143 (FIRST, so they co-reside with the pixel stream)
// pixel part: 2048 blocks = [side(2)][b(8)][half(2)][blk64(64)], bid 144..2191
#define NHYPB (2 * NBK)
#define NPIXB 2048
#define NTOTB (NHYPB + NPIXB)
#define NVB_SIDE 1024       // vote partials per side
#define NSB_SIDE 512        // seg/cnt partials per side (half==0 blocks)

// ws layout (floats); ws[0] = completion counter (int), zeroed by memset node
#define OFS_VOTE 64                          // [2][NVB_SIDE]
#define OFS_CNT  (OFS_VOTE + 2 * NVB_SIDE)   // [2][NSB_SIDE]
#define OFS_SEG  (OFS_CNT  + 2 * NSB_SIDE)   // [2][NSB_SIDE]
#define OFS_KP   (OFS_SEG  + 2 * NSB_SIDE)   // [2][NBK]
#define OFS_ENT  (OFS_KP   + 2 * NBK)        // [2][NBK]
#define OFS_Y    (OFS_ENT  + 2 * NBK)        // [2][NBK]

// native clang vector types (accepted by __builtin_nontemporal_load)
typedef float fx4 __attribute__((ext_vector_type(4)));
typedef int   ix4 __attribute__((ext_vector_type(4)));

// ---- Threefry-2x32, 20 rounds (JAX-compatible) ----
__host__ __device__ inline void tf2x32(uint32_t k0, uint32_t k1,
                                       uint32_t x0, uint32_t x1,
                                       uint32_t& o0, uint32_t& o1) {
  uint32_t ks2 = k0 ^ k1 ^ 0x1BD11BDAu;
  x0 += k0; x1 += k1;
#define TFR(r) { x0 += x1; x1 = (x1 << (r)) | (x1 >> (32 - (r))); x1 ^= x0; }
  TFR(13) TFR(15) TFR(26) TFR(6)   x0 += k1;  x1 += ks2 + 1u;
  TFR(17) TFR(29) TFR(16) TFR(24)  x0 += ks2; x1 += k0 + 2u;
  TFR(13) TFR(15) TFR(26) TFR(6)   x0 += k0;  x1 += k1 + 3u;
  TFR(17) TFR(29) TFR(16) TFR(24)  x0 += k1;  x1 += ks2 + 4u;
  TFR(13) TFR(15) TFR(26) TFR(6)   x0 += ks2; x1 += k0 + 5u;
#undef TFR
  o0 = x0; o1 = x1;
}

__device__ inline float blk_sum(float v, float* sm) {
  int t = threadIdx.x;
  sm[t] = v; __syncthreads();
  for (int off = 128; off > 0; off >>= 1) {
    if (t < off) sm[t] += sm[t + off];
    __syncthreads();
  }
  float r = sm[0]; __syncthreads();
  return r;
}

__device__ inline float sl1(float x, float y, float w) {
  const float dd = fabsf(x - y) * w;
  return (dd < 1.f) ? 0.5f * dd * dd : dd - 0.5f;
}

__device__ inline float nll2(float s0, float s1, int lbl) {
  const float mx = fmaxf(s0, s1);
  const float mn = fminf(s0, s1);
  const float l = mx + logf(1.0f + expf(mn - mx));
  return l - (lbl ? s1 : s0);
}

// non-temporal (L2-bypass) vector loads for streamed data
__device__ inline fx4 ldnt4(const float* p) {
  return __builtin_nontemporal_load((const fx4*)p);
}
__device__ inline ix4 ldnt4i(const int* p) {
  return __builtin_nontemporal_load((const ix4*)p);
}

// cross-XCD partials via AGENT-scope (device) relaxed atomics — reach the
// device coherence point without L2 flushes and without SYSTEM-scope cost
__device__ inline void st_dev(float* p, float v) {
  __hip_atomic_store(p, v, __ATOMIC_RELAXED, __HIP_MEMORY_SCOPE_AGENT);
}
__device__ inline float ld_dev(const float* p) {
  return __hip_atomic_load(p, __ATOMIC_RELAXED, __HIP_MEMORY_SCOPE_AGENT);
}

// ---- Fused kernel: hyp blocks (0..143) + pixel blocks + elected final ----
__global__ __launch_bounds__(256, 8) void fused_kernel(
    const float* __restrict__ vpL, const float* __restrict__ vgL,
    const int*   __restrict__ mkL, const float* __restrict__ sgL,
    const float* __restrict__ vpR, const float* __restrict__ vgR,
    const int*   __restrict__ mkR, const float* __restrict__ sgR,
    const float* __restrict__ scL, const float* __restrict__ kpL,
    const float* __restrict__ k2L, const float* __restrict__ ofL,
    const float* __restrict__ scR, const float* __restrict__ kpR,
    const float* __restrict__ k2R, const float* __restrict__ ofR,
    const float* __restrict__ aPtr, const int* __restrict__ epochPtr,
    uint32_t kLa, uint32_t kLb, uint32_t kRa, uint32_t kRb,
    float* __restrict__ ws, float* __restrict__ out) {
  const int t   = threadIdx.x;
  const int bid = blockIdx.x;
  __shared__ float sm[256];
  __shared__ int   si[256];

  if (bid >= NHYPB) {
    // ================= pixel path (identical to R6's proven config) ========
    const int pb    = bid - NHYPB;         // 0..2047
    const int side  = pb >> 10;
    const int v     = pb & 1023;
    const int b     = v >> 7;
    const int half  = (v >> 6) & 1;
    const int blk64 = v & 63;
    const int hwq   = blk64 * 256 + t;     // quad index 0..16383

    const float* vp = side ? vpR : vpL;
    const float* vg = side ? vgR : vgL;
    const int*   mk = side ? mkR : mkL;
    const float* sg = side ? sgR : sgL;

    // mask once
    const ix4 m4 = ldnt4i(mk + ((size_t)b << 16) + ((size_t)hwq << 2));
    const float w0 = (float)m4.x, w1 = (float)m4.y, w2 = (float)m4.z, w3 = (float)m4.w;

    // seg loads issued early (half==0 blocks only)
    fx4 s0 = (fx4)0.f, s1 = (fx4)0.f;
    if (half == 0) {
      const size_t soff = ((size_t)b << 17) + ((size_t)hwq << 2);
      s0 = ldnt4(sg + soff);
      s1 = ldnt4(sg + soff + HWPIX);
    }

    // channel walk: c = half*9 + j, j = 0..8
    const size_t pbase = ((size_t)(b * NCH + half * 9) << 16) + ((size_t)hwq << 2);
    const float* pp = vp + pbase;
    const float* qq = vg + pbase;

    fx4 Pa = ldnt4(pp);              fx4 Qa = ldnt4(qq);
    fx4 Pb = ldnt4(pp + HWPIX);      fx4 Qb = ldnt4(qq + HWPIX);

    float acc = 0.f;
#pragma unroll
    for (int j = 0; j < 9; ++j) {
      fx4 pc, qc;
      if ((j & 1) == 0) {
        pc = Pa; qc = Qa;
        if (j + 2 < 9) { Pa = ldnt4(pp + (size_t)(j + 2) * HWPIX); Qa = ldnt4(qq + (size_t)(j + 2) * HWPIX); }
      } else {
        pc = Pb; qc = Qb;
        if (j + 2 < 9) { Pb = ldnt4(pp + (size_t)(j + 2) * HWPIX); Qb = ldnt4(qq + (size_t)(j + 2) * HWPIX); }
      }
      acc += sl1(pc.x, qc.x, w0);
      acc += sl1(pc.y, qc.y, w1);
      acc += sl1(pc.z, qc.z, w2);
      acc += sl1(pc.w, qc.w, w3);
    }

    const float rvote = blk_sum(acc, sm);
    if (t == 0) st_dev(&ws[OFS_VOTE + side * NVB_SIDE + v], rvote);

    if (half == 0) {
      float seg = 0.f;
      seg += nll2(s0.x, s1.x, m4.x);
      seg += nll2(s0.y, s1.y, m4.y);
      seg += nll2(s0.z, s1.z, m4.z);
      seg += nll2(s0.w, s1.w, m4.w);
      const float cnt = w0 + w1 + w2 + w3;
      const float rcnt = blk_sum(cnt, sm);
      const float rseg = blk_sum(seg, sm);
      if (t == 0) {
        const int s = b * 64 + blk64;
        st_dev(&ws[OFS_CNT + side * NSB_SIDE + s], rcnt);
        st_dev(&ws[OFS_SEG + side * NSB_SIDE + s], rseg);
      }
    }
  } else {
    // ================= hyp path (bid 0..143 — co-resident from t0) ========
    const int side = bid / NBK;
    const int bk   = bid % NBK;         // 0..71
    const float* sc = side ? scR : scL;
    const float* kp = side ? kpR : kpL;
    const float* k2 = side ? k2R : k2L;
    const float* of = side ? ofR : ofL;
    const uint32_t K0 = side ? kRa : kLa;
    const uint32_t K1 = side ? kRb : kLb;
    const int b = bk / NK, k = bk % NK;
    const float a = aPtr[0];
    const float kx = k2[(b * NK + k) * 2 + 0];
    const float ky = k2[(b * NK + k) * 2 + 1];
    const float2* kp2 = (const float2*)kp;

    float s[4], d[4], gv[4];
#pragma unroll
    for (int j = 0; j < 4; ++j) {
      const int n = t + j * 256;
      const size_t idx = ((size_t)b * NHYP + n) * NK + k;   // flat index of (b,n,k)
      s[j] = a * sc[idx];
      const float2 xy = kp2[idx];
      const float dx = xy.x - kx, dy = xy.y - ky;
      d[j] = sqrtf(dx * dx + dy * dy);
      // JAX partitionable random bits: bits = out0 ^ out1 of threefry(key, (0, flat_idx))
      uint32_t o0, o1;
      tf2x32(K0, K1, 0u, (uint32_t)idx, o0, o1);
      const uint32_t bits = o0 ^ o1;
      float u = __uint_as_float((bits >> 9) | 0x3F800000u) - 1.0f;   // [0,1)
      u = fmaxf(TINYF, u * (1.0f - TINYF) + TINYF);                  // uniform(tiny, 1)
      gv[j] = -logf(-logf(u)) + s[j];                                // gumbel + logits
    }

    // block max of logits
    float mx = fmaxf(fmaxf(s[0], s[1]), fmaxf(s[2], s[3]));
    sm[t] = mx; __syncthreads();
    for (int off = 128; off > 0; off >>= 1) {
      if (t < off) sm[t] = fmaxf(sm[t], sm[t + off]);
      __syncthreads();
    }
    mx = sm[0]; __syncthreads();

    float Z = 0.f, Sd = 0.f, Ss = 0.f;
#pragma unroll
    for (int j = 0; j < 4; ++j) {
      const float e = expf(s[j] - mx);
      Z  += e;
      Sd += e * d[j];
      Ss += e * (s[j] - mx);
    }
    Z  = blk_sum(Z, sm);
    Sd = blk_sum(Sd, sm);
    Ss = blk_sum(Ss, sm);

    // argmax of gumbel+logits, first-index tie-break (matches jnp.argmax)
    float bv = gv[0]; int bi = t;
#pragma unroll
    for (int j = 1; j < 4; ++j) {
      const int n = t + j * 256;
      if (gv[j] > bv) { bv = gv[j]; bi = n; }
    }
    sm[t] = bv; si[t] = bi; __syncthreads();
    for (int off = 128; off > 0; off >>= 1) {
      if (t < off) {
        const float v2 = sm[t + off]; const int i2 = si[t + off];
        if (v2 > sm[t] || (v2 == sm[t] && i2 < si[t])) { sm[t] = v2; si[t] = i2; }
      }
      __syncthreads();
    }

    if (t == 0) {
      st_dev(&ws[OFS_KP  + side * NBK + bk], Sd / Z);
      st_dev(&ws[OFS_ENT + side * NBK + bk], (logf(Z) - Ss / Z) * INV_LOG2);
      const int n = si[0];
      st_dev(&ws[OFS_Y + side * NBK + bk],
             kp2[((size_t)b * NHYP + n) * NK + k].y + of[b * 2 + 1]);
    }
  }

  // ==== completion count; elected (last) block runs the final reduce =======
  __shared__ int isLast;
  asm volatile("s_waitcnt vmcnt(0)" ::: "memory");  // partial stores committed
  if (t == 0) {
    const int c = atomicAdd((int*)ws, 1);           // device-scope, fast (m20)
    isLast = (c == NTOTB - 1);
  }
  __syncthreads();
  if (!isLast) return;

  float voteS[2], cntS[2], segS[2], kpS[2], entS[2];
  for (int side = 0; side < 2; ++side) {
    float a;
    a = 0.f; for (int j = t; j < NVB_SIDE; j += 256) a += ld_dev(&ws[OFS_VOTE + side * NVB_SIDE + j]);
    voteS[side] = blk_sum(a, sm);
    a = 0.f; for (int j = t; j < NSB_SIDE; j += 256) a += ld_dev(&ws[OFS_CNT + side * NSB_SIDE + j]);
    cntS[side] = blk_sum(a, sm);
    a = 0.f; for (int j = t; j < NSB_SIDE; j += 256) a += ld_dev(&ws[OFS_SEG + side * NSB_SIDE + j]);
    segS[side] = blk_sum(a, sm);
    a = (t < NBK) ? ld_dev(&ws[OFS_KP + side * NBK + t]) : 0.f;
    kpS[side] = blk_sum(a, sm);
    a = 0.f;
    if (t < 8) {
      float es = 0.f;
      for (int k = 0; k < NK; ++k) es += ld_dev(&ws[OFS_ENT + side * NBK + t * NK + k]);
      a = fabsf(es / (float)NK - 6.0f);
    }
    entS[side] = blk_sum(a, sm);
  }
  float e = 0.f;
  if (t < NBK) {
    const float dy = fabsf(ld_dev(&ws[OFS_Y + t]) - ld_dev(&ws[OFS_Y + NBK + t]));
    e = isfinite(dy) ? dy : 0.f;
  }
  const float epiSum = blk_sum(e, sm);

  if (t == 0) {
    const float voteL = (cntS[0] > 0.f) ? voteS[0] / fmaxf(cntS[0], 1.f) / (float)NCH : voteS[0];
    const float voteR = (cntS[1] > 0.f) ? voteS[1] / fmaxf(cntS[1], 1.f) / (float)NCH : voteS[1];
    const float segL = segS[0] / 524288.f;
    const float segR = segS[1] / 524288.f;
    const float kpLm = kpS[0] / (float)NBK, kpRm = kpS[1] / (float)NBK;
    const float entL = entS[0] / 8.f, entR = entS[1] / 8.f;

    const float vote_loss = 0.5f * (voteL + voteR);
    const float seg_loss  = 0.5f * (segL + segR);
    const float kp_loss   = 0.5f * (kpLm + kpRm);
    const float ent_loss  = 0.5f * (entL + entR);
    const float kp_w  = 1.f / (1.f + expf(-0.5f * (20.f - kp_loss)));
    const float vote_w = 1.f - kp_w;
    float vertex;
    if (epochPtr[0] > 49) {
      const float epi = epiSum / (float)NBK;
      vertex = kp_w * (kp_loss + epi) + vote_w * vote_loss;
    } else {
      vertex = kp_w * kp_loss + vote_w * vote_loss;
    }
    out[0] = vertex + ent_loss + seg_loss;
  }
}

extern "C" void kernel_launch(void* const* d_in, const int* in_sizes, int n_in,
                              void* d_out, int out_size, void* d_ws, size_t ws_size,
                              hipStream_t stream) {
  (void)in_sizes; (void)n_in; (void)out_size; (void)ws_size;
  const float* vpL = (const float*)d_in[0];
  const float* vgL = (const float*)d_in[1];
  const int*   mkL = (const int*)  d_in[2];
  const float* sgL = (const float*)d_in[3];
  const float* kpL = (const float*)d_in[4];
  const float* scL = (const float*)d_in[5];
  const float* k2L = (const float*)d_in[6];
  const float* ofL = (const float*)d_in[7];
  const float* vpR = (const float*)d_in[8];
  const float* vgR = (const float*)d_in[9];
  const int*   mkR = (const int*)  d_in[10];
  const float* sgR = (const float*)d_in[11];
  const float* kpR = (const float*)d_in[12];
  const float* scR = (const float*)d_in[13];
  const float* k2R = (const float*)d_in[14];
  const float* ofR = (const float*)d_in[15];
  const float* aP  = (const float*)d_in[16];
  const int*   epP = (const int*)  d_in[17];
  float* ws  = (float*)d_ws;
  float* out = (float*)d_out;

  // jax.random.split(jax.random.key(1234)) — partitionable ("foldlike") split:
  // kL = threefry(key, (0,0)), kR = threefry(key, (0,1)), key = [0, 1234]
  uint32_t kLa, kLb, kRa, kRb;
  tf2x32(0u, 1234u, 0u, 0u, kLa, kLb);
  tf2x32(0u, 1234u, 0u, 1u, kRa, kRb);

  // zero the completion counter (graph-capturable memset node)
  hipMemsetAsync(ws, 0, sizeof(int), stream);

  fused_kernel<<<NTOTB, 256, 0, stream>>>(
      vpL, vgL, mkL, sgL, vpR, vgR, mkR, sgR,
      scL, kpL, k2L, ofL, scR, kpR, k2R, ofR,
      aP, epP, kLa, kLb, kRa, kRb, ws, out);
}

// Round 11
// 48.287 us; speedup vs baseline: 7.6340x; 1.3107x over previous
//
#include <hip/hip_runtime.h>
#include <stdint.h>
#include <math.h>

// Problem geometry (fixed by reference)
#define HWPIX 65536         // 256*256
#define NCH   18
#define NHYP  1024
#define NK    9
#define NBK   72            // B*K = 8*9
#define INV_LOG2 1.4426950408889634f
#define TINYF 1.1754943508222875e-38f

// hyp part: blocks 0..143; pixel part: 2048 blocks, bid 144..2191
#define NHYPB (2 * NBK)
#define NPIXB 2048
#define NTOTB (NHYPB + NPIXB)     // 2192 = 16*69 + 16*68
#define NVB_SIDE 1024       // vote partials per side
#define NSB_SIDE 512        // seg/cnt partials per side (half==0 blocks)

// ws layout (floats).
// [0]: master counter; [8 + g*32] g=0..31: group counters (one per 128B line).
// memset zeroes bytes [0, 4096) each launch.
#define CTRG(g)  (8 + (g) * 32)
#define OFS_VOTE 1024                        // [2][NVB_SIDE]
#define OFS_CNT  (OFS_VOTE + 2 * NVB_SIDE)   // [2][NSB_SIDE]
#define OFS_SEG  (OFS_CNT  + 2 * NSB_SIDE)   // [2][NSB_SIDE]
#define OFS_KP   (OFS_SEG  + 2 * NSB_SIDE)   // [2][NBK]
#define OFS_ENT  (OFS_KP   + 2 * NBK)        // [2][NBK]
#define OFS_Y    (OFS_ENT  + 2 * NBK)        // [2][NBK]

// native clang vector types (accepted by __builtin_nontemporal_load)
typedef float fx4 __attribute__((ext_vector_type(4)));
typedef int   ix4 __attribute__((ext_vector_type(4)));

// ---- Threefry-2x32, 20 rounds (JAX-compatible) ----
__host__ __device__ inline void tf2x32(uint32_t k0, uint32_t k1,
                                       uint32_t x0, uint32_t x1,
                                       uint32_t& o0, uint32_t& o1) {
  uint32_t ks2 = k0 ^ k1 ^ 0x1BD11BDAu;
  x0 += k0; x1 += k1;
#define TFR(r) { x0 += x1; x1 = (x1 << (r)) | (x1 >> (32 - (r))); x1 ^= x0; }
  TFR(13) TFR(15) TFR(26) TFR(6)   x0 += k1;  x1 += ks2 + 1u;
  TFR(17) TFR(29) TFR(16) TFR(24)  x0 += ks2; x1 += k0 + 2u;
  TFR(13) TFR(15) TFR(26) TFR(6)   x0 += k0;  x1 += k1 + 3u;
  TFR(17) TFR(29) TFR(16) TFR(24)  x0 += k1;  x1 += ks2 + 4u;
  TFR(13) TFR(15) TFR(26) TFR(6)   x0 += ks2; x1 += k0 + 5u;
#undef TFR
  o0 = x0; o1 = x1;
}

__device__ inline float blk_sum(float v, float* sm) {
  int t = threadIdx.x;
  sm[t] = v; __syncthreads();
  for (int off = 128; off > 0; off >>= 1) {
    if (t < off) sm[t] += sm[t + off];
    __syncthreads();
  }
  float r = sm[0]; __syncthreads();
  return r;
}

__device__ inline float sl1(float x, float y, float w) {
  const float dd = fabsf(x - y) * w;
  return (dd < 1.f) ? 0.5f * dd * dd : dd - 0.5f;
}

__device__ inline float nll2(float s0, float s1, int lbl) {
  const float mx = fmaxf(s0, s1);
  const float mn = fminf(s0, s1);
  const float l = mx + logf(1.0f + expf(mn - mx));
  return l - (lbl ? s1 : s0);
}

// non-temporal (L2-bypass) vector loads for streamed data
__device__ inline fx4 ldnt4(const float* p) {
  return __builtin_nontemporal_load((const fx4*)p);
}
__device__ inline ix4 ldnt4i(const int* p) {
  return __builtin_nontemporal_load((const ix4*)p);
}

// cross-XCD partials via AGENT-scope (device) relaxed atomics
__device__ inline void st_dev(float* p, float v) {
  __hip_atomic_store(p, v, __ATOMIC_RELAXED, __HIP_MEMORY_SCOPE_AGENT);
}
__device__ inline float ld_dev(const float* p) {
  return __hip_atomic_load(p, __ATOMIC_RELAXED, __HIP_MEMORY_SCOPE_AGENT);
}

// ---- Fused kernel: hyp blocks (0..143) + pixel blocks + elected final ----
__global__ __launch_bounds__(256, 8) void fused_kernel(
    const float* __restrict__ vpL, const float* __restrict__ vgL,
    const int*   __restrict__ mkL, const float* __restrict__ sgL,
    const float* __restrict__ vpR, const float* __restrict__ vgR,
    const int*   __restrict__ mkR, const float* __restrict__ sgR,
    const float* __restrict__ scL, const float* __restrict__ kpL,
    const float* __restrict__ k2L, const float* __restrict__ ofL,
    const float* __restrict__ scR, const float* __restrict__ kpR,
    const float* __restrict__ k2R, const float* __restrict__ ofR,
    const float* __restrict__ aPtr, const int* __restrict__ epochPtr,
    uint32_t kLa, uint32_t kLb, uint32_t kRa, uint32_t kRb,
    float* __restrict__ ws, float* __restrict__ out) {
  const int t   = threadIdx.x;
  const int bid = blockIdx.x;
  __shared__ float sm[256];
  __shared__ int   si[256];

  if (bid >= NHYPB) {
    // ================= pixel path (identical to R6's proven config) ========
    const int pb    = bid - NHYPB;         // 0..2047
    const int side  = pb >> 10;
    const int v     = pb & 1023;
    const int b     = v >> 7;
    const int half  = (v >> 6) & 1;
    const int blk64 = v & 63;
    const int hwq   = blk64 * 256 + t;     // quad index 0..16383

    const float* vp = side ? vpR : vpL;
    const float* vg = side ? vgR : vgL;
    const int*   mk = side ? mkR : mkL;
    const float* sg = side ? sgR : sgL;

    // mask once
    const ix4 m4 = ldnt4i(mk + ((size_t)b << 16) + ((size_t)hwq << 2));
    const float w0 = (float)m4.x, w1 = (float)m4.y, w2 = (float)m4.z, w3 = (float)m4.w;

    // seg loads issued early (half==0 blocks only)
    fx4 s0 = (fx4)0.f, s1 = (fx4)0.f;
    if (half == 0) {
      const size_t soff = ((size_t)b << 17) + ((size_t)hwq << 2);
      s0 = ldnt4(sg + soff);
      s1 = ldnt4(sg + soff + HWPIX);
    }

    // channel walk: c = half*9 + j, j = 0..8
    const size_t pbase = ((size_t)(b * NCH + half * 9) << 16) + ((size_t)hwq << 2);
    const float* pp = vp + pbase;
    const float* qq = vg + pbase;

    fx4 Pa = ldnt4(pp);              fx4 Qa = ldnt4(qq);
    fx4 Pb = ldnt4(pp + HWPIX);      fx4 Qb = ldnt4(qq + HWPIX);

    float acc = 0.f;
#pragma unroll
    for (int j = 0; j < 9; ++j) {
      fx4 pc, qc;
      if ((j & 1) == 0) {
        pc = Pa; qc = Qa;
        if (j + 2 < 9) { Pa = ldnt4(pp + (size_t)(j + 2) * HWPIX); Qa = ldnt4(qq + (size_t)(j + 2) * HWPIX); }
      } else {
        pc = Pb; qc = Qb;
        if (j + 2 < 9) { Pb = ldnt4(pp + (size_t)(j + 2) * HWPIX); Qb = ldnt4(qq + (size_t)(j + 2) * HWPIX); }
      }
      acc += sl1(pc.x, qc.x, w0);
      acc += sl1(pc.y, qc.y, w1);
      acc += sl1(pc.z, qc.z, w2);
      acc += sl1(pc.w, qc.w, w3);
    }

    const float rvote = blk_sum(acc, sm);
    if (t == 0) st_dev(&ws[OFS_VOTE + side * NVB_SIDE + v], rvote);

    if (half == 0) {
      float seg = 0.f;
      seg += nll2(s0.x, s1.x, m4.x);
      seg += nll2(s0.y, s1.y, m4.y);
      seg += nll2(s0.z, s1.z, m4.z);
      seg += nll2(s0.w, s1.w, m4.w);
      const float cnt = w0 + w1 + w2 + w3;
      const float rcnt = blk_sum(cnt, sm);
      const float rseg = blk_sum(seg, sm);
      if (t == 0) {
        const int s = b * 64 + blk64;
        st_dev(&ws[OFS_CNT + side * NSB_SIDE + s], rcnt);
        st_dev(&ws[OFS_SEG + side * NSB_SIDE + s], rseg);
      }
    }
  } else {
    // ================= hyp path (bid 0..143) =================
    const int side = bid / NBK;
    const int bk   = bid % NBK;         // 0..71
    const float* sc = side ? scR : scL;
    const float* kp = side ? kpR : kpL;
    const float* k2 = side ? k2R : k2L;
    const float* of = side ? ofR : ofL;
    const uint32_t K0 = side ? kRa : kLa;
    const uint32_t K1 = side ? kRb : kLb;
    const int b = bk / NK, k = bk % NK;
    const float a = aPtr[0];
    const float kx = k2[(b * NK + k) * 2 + 0];
    const float ky = k2[(b * NK + k) * 2 + 1];
    const float2* kp2 = (const float2*)kp;

    float s[4], d[4], gv[4];
#pragma unroll
    for (int j = 0; j < 4; ++j) {
      const int n = t + j * 256;
      const size_t idx = ((size_t)b * NHYP + n) * NK + k;   // flat index of (b,n,k)
      s[j] = a * sc[idx];
      const float2 xy = kp2[idx];
      const float dx = xy.x - kx, dy = xy.y - ky;
      d[j] = sqrtf(dx * dx + dy * dy);
      // JAX partitionable random bits: bits = out0 ^ out1 of threefry(key, (0, flat_idx))
      uint32_t o0, o1;
      tf2x32(K0, K1, 0u, (uint32_t)idx, o0, o1);
      const uint32_t bits = o0 ^ o1;
      float u = __uint_as_float((bits >> 9) | 0x3F800000u) - 1.0f;   // [0,1)
      u = fmaxf(TINYF, u * (1.0f - TINYF) + TINYF);                  // uniform(tiny, 1)
      gv[j] = -logf(-logf(u)) + s[j];                                // gumbel + logits
    }

    // block max of logits
    float mx = fmaxf(fmaxf(s[0], s[1]), fmaxf(s[2], s[3]));
    sm[t] = mx; __syncthreads();
    for (int off = 128; off > 0; off >>= 1) {
      if (t < off) sm[t] = fmaxf(sm[t], sm[t + off]);
      __syncthreads();
    }
    mx = sm[0]; __syncthreads();

    float Z = 0.f, Sd = 0.f, Ss = 0.f;
#pragma unroll
    for (int j = 0; j < 4; ++j) {
      const float e = expf(s[j] - mx);
      Z  += e;
      Sd += e * d[j];
      Ss += e * (s[j] - mx);
    }
    Z  = blk_sum(Z, sm);
    Sd = blk_sum(Sd, sm);
    Ss = blk_sum(Ss, sm);

    // argmax of gumbel+logits, first-index tie-break (matches jnp.argmax)
    float bv = gv[0]; int bi = t;
#pragma unroll
    for (int j = 1; j < 4; ++j) {
      const int n = t + j * 256;
      if (gv[j] > bv) { bv = gv[j]; bi = n; }
    }
    sm[t] = bv; si[t] = bi; __syncthreads();
    for (int off = 128; off > 0; off >>= 1) {
      if (t < off) {
        const float v2 = sm[t + off]; const int i2 = si[t + off];
        if (v2 > sm[t] || (v2 == sm[t] && i2 < si[t])) { sm[t] = v2; si[t] = i2; }
      }
      __syncthreads();
    }

    if (t == 0) {
      st_dev(&ws[OFS_KP  + side * NBK + bk], Sd / Z);
      st_dev(&ws[OFS_ENT + side * NBK + bk], (logf(Z) - Ss / Z) * INV_LOG2);
      const int n = si[0];
      st_dev(&ws[OFS_Y + side * NBK + bk],
             kp2[((size_t)b * NHYP + n) * NK + k].y + of[b * 2 + 1]);
    }
  }

  // ==== two-level completion tree; elected block runs the final reduce =====
  __shared__ int isLast;
  asm volatile("s_waitcnt vmcnt(0)" ::: "memory");  // partial stores committed
  if (t == 0) {
    int last = 0;
    int* ctr = (int*)ws;
    const int g = bid & 31;
    const int quota = (g < 16) ? 69 : 68;           // 16*69 + 16*68 = 2192
    const int c = atomicAdd(&ctr[CTRG(g)], 1);      // per-group line, low contention
    if (c == quota - 1) {
      const int m = atomicAdd(&ctr[0], 1);          // 32 ops total
      last = (m == 31);
    }
    isLast = last;
  }
  __syncthreads();
  if (!isLast) return;

  // ---- final reduce (fixed order -> deterministic, whichever block runs it)
  float voteS[2], cntS[2], segS[2], kpS[2], entS[2];
  for (int side = 0; side < 2; ++side) {
    float tmp[4];
#pragma unroll
    for (int i = 0; i < 4; ++i)
      tmp[i] = ld_dev(&ws[OFS_VOTE + side * NVB_SIDE + t + i * 256]);
    voteS[side] = blk_sum((tmp[0] + tmp[1]) + (tmp[2] + tmp[3]), sm);

    float c0 = ld_dev(&ws[OFS_CNT + side * NSB_SIDE + t]);
    float c1 = ld_dev(&ws[OFS_CNT + side * NSB_SIDE + t + 256]);
    cntS[side] = blk_sum(c0 + c1, sm);

    float g0 = ld_dev(&ws[OFS_SEG + side * NSB_SIDE + t]);
    float g1 = ld_dev(&ws[OFS_SEG + side * NSB_SIDE + t + 256]);
    segS[side] = blk_sum(g0 + g1, sm);

    float a = (t < NBK) ? ld_dev(&ws[OFS_KP + side * NBK + t]) : 0.f;
    kpS[side] = blk_sum(a, sm);

    a = 0.f;
    if (t < 8) {
      float es = 0.f;
      for (int k = 0; k < NK; ++k) es += ld_dev(&ws[OFS_ENT + side * NBK + t * NK + k]);
      a = fabsf(es / (float)NK - 6.0f);
    }
    entS[side] = blk_sum(a, sm);
  }
  float e = 0.f;
  if (t < NBK) {
    const float dy = fabsf(ld_dev(&ws[OFS_Y + t]) - ld_dev(&ws[OFS_Y + NBK + t]));
    e = isfinite(dy) ? dy : 0.f;
  }
  const float epiSum = blk_sum(e, sm);

  if (t == 0) {
    const float voteL = (cntS[0] > 0.f) ? voteS[0] / fmaxf(cntS[0], 1.f) / (float)NCH : voteS[0];
    const float voteR = (cntS[1] > 0.f) ? voteS[1] / fmaxf(cntS[1], 1.f) / (float)NCH : voteS[1];
    const float segL = segS[0] / 524288.f;
    const float segR = segS[1] / 524288.f;
    const float kpLm = kpS[0] / (float)NBK, kpRm = kpS[1] / (float)NBK;
    const float entL = entS[0] / 8.f, entR = entS[1] / 8.f;

    const float vote_loss = 0.5f * (voteL + voteR);
    const float seg_loss  = 0.5f * (segL + segR);
    const float kp_loss   = 0.5f * (kpLm + kpRm);
    const float ent_loss  = 0.5f * (entL + entR);
    const float kp_w  = 1.f / (1.f + expf(-0.5f * (20.f - kp_loss)));
    const float vote_w = 1.f - kp_w;
    float vertex;
    if (epochPtr[0] > 49) {
      const float epi = epiSum / (float)NBK;
      vertex = kp_w * (kp_loss + epi) + vote_w * vote_loss;
    } else {
      vertex = kp_w * kp_loss + vote_w * vote_loss;
    }
    out[0] = vertex + ent_loss + seg_loss;
  }
}

extern "C" void kernel_launch(void* const* d_in, const int* in_sizes, int n_in,
                              void* d_out, int out_size, void* d_ws, size_t ws_size,
                              hipStream_t stream) {
  (void)in_sizes; (void)n_in; (void)out_size; (void)ws_size;
  const float* vpL = (const float*)d_in[0];
  const float* vgL = (const float*)d_in[1];
  const int*   mkL = (const int*)  d_in[2];
  const float* sgL = (const float*)d_in[3];
  const float* kpL = (const float*)d_in[4];
  const float* scL = (const float*)d_in[5];
  const float* k2L = (const float*)d_in[6];
  const float* ofL = (const float*)d_in[7];
  const float* vpR = (const float*)d_in[8];
  const float* vgR = (const float*)d_in[9];
  const int*   mkR = (const int*)  d_in[10];
  const float* sgR = (const float*)d_in[11];
  const float* kpR = (const float*)d_in[12];
  const float* scR = (const float*)d_in[13];
  const float* k2R = (const float*)d_in[14];
  const float* ofR = (const float*)d_in[15];
  const float* aP  = (const float*)d_in[16];
  const int*   epP = (const int*)  d_in[17];
  float* ws  = (float*)d_ws;
  float* out = (float*)d_out;

  // jax.random.split(jax.random.key(1234)) — partitionable ("foldlike") split:
  // kL = threefry(key, (0,0)), kR = threefry(key, (0,1)), key = [0, 1234]
  uint32_t kLa, kLb, kRa, kRb;
  tf2x32(0u, 1234u, 0u, 0u, kLa, kLb);
  tf2x32(0u, 1234u, 0u, 1u, kRa, kRb);

  // zero the counter tree (graph-capturable memset node; bytes [0,4096))
  hipMemsetAsync(ws, 0, 4096, stream);

  fused_kernel<<<NTOTB, 256, 0, stream>>>(
      vpL, vgL, mkL, sgL, vpR, vgR, mkR, sgR,
      scL, kpL, k2L, ofL, scR, kpR, k2R, ofR,
      aP, epP, kLa, kLb, kRa, kRb, ws, out);
}